// Round 1
// baseline (5302.874 us; speedup 1.0000x reference)
//
#include <hip/hip_runtime.h>
#include <hip/hip_bf16.h>

#define B_ 256
#define T_ 100
#define EMBED_ 36
#define DM_ 72
#define H_ 4
#define E_ 18
#define PATCH_ 16
#define STRIDE_ 8
#define SEQ_ 101   // T+1
#define PN_ 12
#define DFF_ 1152
#define FFCH_ 384  // FF K-chunk (3 chunks of 384)

// ---------------- helpers ----------------

__device__ __forceinline__ float block_sum(float v, float* red) {
  int tid = threadIdx.x;
  red[tid] = v;
  __syncthreads();
  for (int s = 128; s > 0; s >>= 1) {
    if (tid < s) red[tid] += red[tid + s];
    __syncthreads();
  }
  float r = red[0];
  __syncthreads();
  return r;
}

__device__ __forceinline__ float pe_val(float periods, int freqs, int idx, int c) {
  int f = (c < freqs) ? c : (c - freqs);
  float ang = 3.14159265358979323846f / periods * exp2f((float)f) * ((float)idx - 1.0f);
  return (c < freqs) ? sinf(ang) : cosf(ang);
}

// jj in [0,36): concat of pe_year(dy)[8], pe_month(mo)[8], pe_day(da)[12], pe_dow(dw)[8]
__device__ __forceinline__ float pos_feat(int jj, int dy, int mo, int da, int dw) {
  if (jj < 8)  return pe_val(10.f, 4, dy, jj);
  if (jj < 16) return pe_val(12.f, 4, mo, jj - 8);
  if (jj < 28) return pe_val(31.f, 6, da, jj - 16);
  return pe_val(7.f, 4, dw, jj - 28);
}

// ---------------- kernel A: preprocess + patch embed ----------------
// one block per batch row b; builds z[(b*72+d), p, j] in zbuf
__global__ __launch_bounds__(256) void prep_kernel(
    const float* __restrict__ history,
    const float* __restrict__ w_nopos, const float* __restrict__ b_nopos,
    const float* __restrict__ w_wpos, const float* __restrict__ b_wpos,
    const float* __restrict__ task_emb,
    const float* __restrict__ w_inp, const float* __restrict__ b_inp,
    const int* __restrict__ ts, const int* __restrict__ target_ts,
    const int* __restrict__ task,
    float* __restrict__ zbuf, float* __restrict__ sbuf, float* __restrict__ d_out)
{
  const int b = blockIdx.x, tid = threadIdx.x;
  __shared__ float hs[SEQ_][73];   // hist, padded stride
  __shared__ float red[256];
  __shared__ float mu[DM_], rsd[DM_];

  const float* x = history + (size_t)b * T_;

  // ---- masked stats of history ----
  float xv = (tid < T_) ? x[tid] : 0.0f;
  bool msk1 = (tid < T_) && (xv != 0.0f);
  float sum1 = block_sum(msk1 ? xv : 0.0f, red);
  float cnt1 = block_sum(msk1 ? 1.0f : 0.0f, red);
  float safe1 = fmaxf(cnt1, 1.0f);
  float mean1 = sum1 / safe1;
  float var1 = block_sum(msk1 ? (xv - mean1) * (xv - mean1) : 0.0f, red) / safe1;
  float std1 = (cnt1 > 0.f) ? sqrtf(var1) : 0.0f;
  float mn1  = (cnt1 > 0.f) ? mean1 : 0.0f;
  float hi = mn1 + 2.0f * std1;
  float cl = (tid < T_) ? fminf(fmaxf(xv, 0.0f), hi) : 0.0f;

  // ---- masked stats of clipped ----
  bool msk2 = (tid < T_) && (cl != 0.0f);
  float sum2 = block_sum(msk2 ? cl : 0.0f, red);
  float cnt2 = block_sum(msk2 ? 1.0f : 0.0f, red);
  float safe2 = fmaxf(cnt2, 1.0f);
  float mean2 = sum2 / safe2;
  float var2 = block_sum(msk2 ? (cl - mean2) * (cl - mean2) : 0.0f, red) / safe2;
  float std2 = (cnt2 > 0.f) ? sqrtf(var2) : 0.0f;
  float mn2  = (cnt2 > 0.f) ? mean2 : 0.0f;
  const float s = mn2 + std2 + 1e-4f;   // EPS
  if (tid == 0) { sbuf[b] = s; d_out[B_ + b] = s; }  // scale output

  const int yr_last = ts[((size_t)b * T_ + (T_ - 1)) * 4 + 0];

  // ---- hist rows 0..99 ----
  for (int o = tid; o < T_ * DM_; o += 256) {
    int t = o / DM_, j = o % DM_;
    float h = fminf(fmaxf(x[t] / s, 0.0f), 3.0f);
    float val;
    if (j < EMBED_) {
      val = fmaxf(h * w_nopos[j] + b_nopos[j], 0.0f);
    } else {
      int jj = j - EMBED_;
      float e1 = fmaxf(h * w_wpos[jj] + b_wpos[jj], 0.0f);
      const int* tr = ts + ((size_t)b * T_ + t) * 4;
      int dy = min(max(yr_last - tr[0], 0), 10);
      val = e1 + pos_feat(jj, dy, tr[1], tr[2], tr[3]);
    }
    hs[t][j] = val;
  }
  // ---- hist row 100 (target token) ----
  if (tid < DM_) {
    int j = tid;
    float te = task_emb[task[b] * EMBED_ + (j < EMBED_ ? j : j - EMBED_)];
    if (j < EMBED_) {
      hs[T_][j] = te;
    } else {
      int jj = j - EMBED_;
      const int* qr = target_ts + (size_t)b * 5;
      int yq = min(max(yr_last - qr[0], 0), 10);
      hs[T_][j] = te + pos_feat(jj, yq, qr[1], qr[2], qr[3]);
    }
  }
  __syncthreads();

  // ---- per-feature norm over the 101 tokens ----
  if (tid < DM_) {
    float acc = 0.f;
    for (int t = 0; t < SEQ_; t++) acc += hs[t][tid];
    float m = acc / (float)SEQ_;
    float v = 0.f;
    for (int t = 0; t < SEQ_; t++) { float d = hs[t][tid] - m; v += d * d; }
    v /= (float)SEQ_;
    mu[tid] = m; rsd[tid] = 1.0f / sqrtf(v + 1e-5f);
  }
  __syncthreads();
  for (int o = tid; o < SEQ_ * DM_; o += 256) {
    int t = o / DM_, d = o % DM_;
    hs[t][d] = (hs[t][d] - mu[d]) * rsd[d];
  }
  __syncthreads();

  // ---- patches @ w_inp + b_inp -> z ----
  for (int o = tid; o < DM_ * PN_ * DM_; o += 256) {
    int j = o % DM_, p = (o / DM_) % PN_, d = o / (DM_ * PN_);
    float acc = b_inp[j];
    #pragma unroll
    for (int i = 0; i < PATCH_; i++) {
      int t = p * STRIDE_ + i;
      if (t > T_) t = T_;       // repeat-last padding
      acc += hs[t][d] * w_inp[i * DM_ + j];
    }
    zbuf[((size_t)(b * DM_ + d) * PN_ + p) * DM_ + j] = acc;
  }
}

// ---------------- kernel B: transformer block, one z-row per block ----------------

__device__ __forceinline__ void layernorm_ip(float zs[PN_][DM_], float* mu, float* rsd,
                                             const float* __restrict__ g,
                                             const float* __restrict__ be, int tid) {
  if (tid < PN_) {
    float acc = 0.f;
    for (int i = 0; i < DM_; i++) acc += zs[tid][i];
    float m = acc / (float)DM_;
    float v = 0.f;
    for (int i = 0; i < DM_; i++) { float d = zs[tid][i] - m; v += d * d; }
    v /= (float)DM_;
    mu[tid] = m; rsd[tid] = 1.0f / sqrtf(v + 1e-5f);
  }
  __syncthreads();
  for (int o = tid; o < PN_ * DM_; o += 256) {
    int l = o / DM_, j = o % DM_;
    zs[l][j] = (zs[l][j] - mu[l]) * rsd[l] * g[j] + be[j];
  }
  __syncthreads();
}

__global__ __launch_bounds__(256) void block_kernel(
    const float* __restrict__ wq, const float* __restrict__ bq,
    const float* __restrict__ wk, const float* __restrict__ bk,
    const float* __restrict__ wv, const float* __restrict__ bv,
    const float* __restrict__ wo, const float* __restrict__ bo,
    const float* __restrict__ w_ff1, const float* __restrict__ b_ff1,
    const float* __restrict__ w_ff2, const float* __restrict__ b_ff2,
    const float* __restrict__ g1, const float* __restrict__ be1,
    const float* __restrict__ g2, const float* __restrict__ be2,
    const float* __restrict__ ge, const float* __restrict__ bee,
    float* __restrict__ zbuf)
{
  const int r = blockIdx.x, tid = threadIdx.x;
  __shared__ float zs[PN_][DM_];
  __shared__ float qq[PN_][DM_];
  __shared__ float kk[PN_][DM_];
  __shared__ float vv[PN_][DM_];
  __shared__ float sc[H_][PN_][PN_];
  __shared__ float mu[PN_], rsd[PN_];
  __shared__ float gch[PN_][FFCH_];

  float* zg = zbuf + (size_t)r * PN_ * DM_;
  for (int o = tid; o < PN_ * DM_; o += 256) (&zs[0][0])[o] = zg[o];
  __syncthreads();

  // ---- QKV: 648 tasks, each = one (matrix, l, 4-wide j group), float4 weight loads ----
  for (int o = tid; o < 3 * PN_ * (DM_ / 4); o += 256) {
    int jg = o % (DM_ / 4);
    int l  = (o / (DM_ / 4)) % PN_;
    int m  = o / (PN_ * (DM_ / 4));
    const float* w = (m == 0) ? wq : (m == 1) ? wk : wv;
    const float* bb = (m == 0) ? bq : (m == 1) ? bk : bv;
    const float4* w4 = reinterpret_cast<const float4*>(w);
    float4 acc = reinterpret_cast<const float4*>(bb)[jg];
    for (int i = 0; i < DM_; i++) {
      float zi = zs[l][i];
      float4 wv4 = w4[i * (DM_ / 4) + jg];
      acc.x += zi * wv4.x; acc.y += zi * wv4.y; acc.z += zi * wv4.z; acc.w += zi * wv4.w;
    }
    float* dst = (m == 0) ? &qq[0][0] : (m == 1) ? &kk[0][0] : &vv[0][0];
    *reinterpret_cast<float4*>(&dst[l * DM_ + jg * 4]) = acc;
  }
  __syncthreads();

  // ---- scores ----
  const float inv_sqrt_e = 0.23570226039551584f;  // 1/sqrt(18)
  for (int o = tid; o < H_ * PN_ * PN_; o += 256) {
    int h = o / (PN_ * PN_), l = (o / PN_) % PN_, s2 = o % PN_;
    float acc = 0.f;
    #pragma unroll
    for (int e = 0; e < E_; e++) acc += qq[l][h * E_ + e] * kk[s2][h * E_ + e];
    sc[h][l][s2] = acc * inv_sqrt_e;
  }
  __syncthreads();
  // ---- softmax over s ----
  if (tid < H_ * PN_) {
    int h = tid / PN_, l = tid % PN_;
    float mx = -1e30f;
    for (int s2 = 0; s2 < PN_; s2++) mx = fmaxf(mx, sc[h][l][s2]);
    float sum = 0.f;
    for (int s2 = 0; s2 < PN_; s2++) { float e2 = expf(sc[h][l][s2] - mx); sc[h][l][s2] = e2; sum += e2; }
    float inv = 1.0f / sum;
    for (int s2 = 0; s2 < PN_; s2++) sc[h][l][s2] *= inv;
  }
  __syncthreads();

  // ---- o = A @ v (into qq; q is dead) ----
  for (int o = tid; o < PN_ * DM_; o += 256) {
    int l = o / DM_, j = o % DM_, h = j / E_;
    float acc = 0.f;
    #pragma unroll
    for (int s2 = 0; s2 < PN_; s2++) acc += sc[h][l][s2] * vv[s2][j];
    qq[l][j] = acc;
  }
  __syncthreads();

  // ---- z += o @ wo + bo ----
  for (int o = tid; o < PN_ * (DM_ / 4); o += 256) {
    int jg = o % (DM_ / 4), l = o / (DM_ / 4);
    const float4* w4 = reinterpret_cast<const float4*>(wo);
    float4 acc = reinterpret_cast<const float4*>(bo)[jg];
    for (int i = 0; i < DM_; i++) {
      float oi = qq[l][i];
      float4 wv4 = w4[i * (DM_ / 4) + jg];
      acc.x += oi * wv4.x; acc.y += oi * wv4.y; acc.z += oi * wv4.z; acc.w += oi * wv4.w;
    }
    float4* zp = reinterpret_cast<float4*>(&zs[l][jg * 4]);
    float4 z0 = *zp;
    z0.x += acc.x; z0.y += acc.y; z0.z += acc.z; z0.w += acc.w;
    *zp = z0;
  }
  __syncthreads();

  layernorm_ip(zs, mu, rsd, g1, be1, tid);

  // ---- FF, K chunked (3 x 384) to keep LDS small ----
  float4 facc = make_float4(0.f, 0.f, 0.f, 0.f);
  const int NT_FF2 = PN_ * (DM_ / 4);   // 216 tasks; thread tid<216 owns task tid
  for (int c = 0; c < 3; c++) {
    // ff1 chunk -> gelu -> gch
    for (int o = tid; o < PN_ * (FFCH_ / 4); o += 256) {
      int kg = o % (FFCH_ / 4), l = o / (FFCH_ / 4);
      const float4* w4 = reinterpret_cast<const float4*>(w_ff1);
      float4 acc = reinterpret_cast<const float4*>(b_ff1)[c * (FFCH_ / 4) + kg];
      for (int i = 0; i < DM_; i++) {
        float zi = zs[l][i];
        float4 wv4 = w4[i * (DFF_ / 4) + c * (FFCH_ / 4) + kg];
        acc.x += zi * wv4.x; acc.y += zi * wv4.y; acc.z += zi * wv4.z; acc.w += zi * wv4.w;
      }
      float4 g4;
      g4.x = 0.5f * acc.x * (1.0f + erff(acc.x * 0.70710678118654752f));
      g4.y = 0.5f * acc.y * (1.0f + erff(acc.y * 0.70710678118654752f));
      g4.z = 0.5f * acc.z * (1.0f + erff(acc.z * 0.70710678118654752f));
      g4.w = 0.5f * acc.w * (1.0f + erff(acc.w * 0.70710678118654752f));
      *reinterpret_cast<float4*>(&gch[l][kg * 4]) = g4;
    }
    __syncthreads();
    // ff2 partial accumulate
    if (tid < NT_FF2) {
      int jg = tid % (DM_ / 4), l = tid / (DM_ / 4);
      const float4* w4 = reinterpret_cast<const float4*>(w_ff2);
      float4 acc = facc;
      for (int k2 = 0; k2 < FFCH_; k2++) {
        float gk = gch[l][k2];
        float4 wv4 = w4[(c * FFCH_ + k2) * (DM_ / 4) + jg];
        acc.x += gk * wv4.x; acc.y += gk * wv4.y; acc.z += gk * wv4.z; acc.w += gk * wv4.w;
      }
      facc = acc;
    }
    __syncthreads();
  }
  if (tid < NT_FF2) {
    int jg = tid % (DM_ / 4), l = tid / (DM_ / 4);
    float4 b4 = reinterpret_cast<const float4*>(b_ff2)[jg];
    float4* zp = reinterpret_cast<float4*>(&zs[l][jg * 4]);
    float4 z0 = *zp;
    z0.x += facc.x + b4.x; z0.y += facc.y + b4.y; z0.z += facc.z + b4.z; z0.w += facc.w + b4.w;
    *zp = z0;
  }
  __syncthreads();

  layernorm_ip(zs, mu, rsd, g2, be2, tid);
  layernorm_ip(zs, mu, rsd, ge, bee, tid);

  for (int o = tid; o < PN_ * DM_; o += 256) zg[o] = (&zs[0][0])[o];
}

// ---------------- kernel C: output projection + head ----------------
__global__ __launch_bounds__(256) void final_kernel(
    const float* __restrict__ zbuf,
    const float* __restrict__ w_outp, const float* __restrict__ b_outp,
    const float* __restrict__ w_head, const float* __restrict__ b_head,
    const float* __restrict__ sbuf, float* __restrict__ d_out)
{
  const int b = blockIdx.x, tid = threadIdx.x;
  const int wave = tid >> 6, lane = tid & 63;
  __shared__ float out0[DM_];
  const float* zb = zbuf + (size_t)b * DM_ * (PN_ * DM_);

  for (int d = wave; d < DM_; d += 4) {
    float acc = 0.f;
    for (int e = lane; e < PN_ * DM_; e += 64) acc += zb[(size_t)d * PN_ * DM_ + e] * w_outp[e];
    #pragma unroll
    for (int m = 32; m > 0; m >>= 1) acc += __shfl_xor(acc, m, 64);
    if (lane == 0) out0[d] = acc + b_outp[0];
  }
  __syncthreads();
  if (tid == 0) {
    float acc = b_head[0];
    for (int d = 0; d < DM_; d++) acc += out0[d] * w_head[d];
    d_out[b] = fmaxf(acc, 0.0f) * sbuf[b];
  }
}

// ---------------- launcher ----------------
extern "C" void kernel_launch(void* const* d_in, const int* in_sizes, int n_in,
                              void* d_out, int out_size, void* d_ws, size_t ws_size,
                              hipStream_t stream) {
  const float* history  = (const float*)d_in[0];
  const float* w_nopos  = (const float*)d_in[1];
  const float* b_nopos  = (const float*)d_in[2];
  const float* w_wpos   = (const float*)d_in[3];
  const float* b_wpos   = (const float*)d_in[4];
  const float* task_emb = (const float*)d_in[5];
  const float* w_inp    = (const float*)d_in[6];
  const float* b_inp    = (const float*)d_in[7];
  const float* wq = (const float*)d_in[8];
  const float* bq = (const float*)d_in[9];
  const float* wk = (const float*)d_in[10];
  const float* bk = (const float*)d_in[11];
  const float* wv = (const float*)d_in[12];
  const float* bv = (const float*)d_in[13];
  const float* wo = (const float*)d_in[14];
  const float* bo = (const float*)d_in[15];
  const float* w_ff1 = (const float*)d_in[16];
  const float* b_ff1 = (const float*)d_in[17];
  const float* w_ff2 = (const float*)d_in[18];
  const float* b_ff2 = (const float*)d_in[19];
  const float* g1  = (const float*)d_in[20];
  const float* be1 = (const float*)d_in[21];
  const float* g2  = (const float*)d_in[22];
  const float* be2 = (const float*)d_in[23];
  const float* ge  = (const float*)d_in[24];
  const float* bee = (const float*)d_in[25];
  const float* w_outp = (const float*)d_in[26];
  const float* b_outp = (const float*)d_in[27];
  const float* w_head = (const float*)d_in[28];
  const float* b_head = (const float*)d_in[29];
  const int* ts        = (const int*)d_in[30];
  const int* target_ts = (const int*)d_in[31];
  const int* task      = (const int*)d_in[32];

  float* out  = (float*)d_out;
  float* zbuf = (float*)d_ws;                                   // 256*72*12*72 f32 = 63.7 MB
  float* sbuf = zbuf + (size_t)B_ * DM_ * PN_ * DM_;            // 256 f32

  prep_kernel<<<B_, 256, 0, stream>>>(history, w_nopos, b_nopos, w_wpos, b_wpos,
      task_emb, w_inp, b_inp, ts, target_ts, task, zbuf, sbuf, out);
  block_kernel<<<B_ * DM_, 256, 0, stream>>>(wq, bq, wk, bk, wv, bv, wo, bo,
      w_ff1, b_ff1, w_ff2, b_ff2, g1, be1, g2, be2, ge, bee, zbuf);
  final_kernel<<<B_, 256, 0, stream>>>(zbuf, w_outp, b_outp, w_head, b_head, sbuf, out);
}

// Round 2
// 915.617 us; speedup vs baseline: 5.7916x; 5.7916x over previous
//
#include <hip/hip_runtime.h>
#include <hip/hip_bf16.h>

#define B_ 256
#define T_ 100
#define EMBED_ 36
#define DM_ 72
#define H_ 4
#define E_ 18
#define PATCH_ 16
#define STRIDE_ 8
#define SEQ_ 101   // T+1
#define PN_ 12
#define DFF_ 1152

#define NTOK 192   // 16 rows * 12 tokens per transformer block
#define KP 96      // K padded (72 -> 96)
#define QS 73      // qkv LDS stride (ushort)

typedef __attribute__((ext_vector_type(8))) short s8v;     // 8 bf16
typedef __attribute__((ext_vector_type(4))) float f32x4;

__device__ __forceinline__ unsigned short f2b(float x) {
  __hip_bfloat16 b = __float2bfloat16(x);
  return __builtin_bit_cast(unsigned short, b);
}
__device__ __forceinline__ float b2f(unsigned short u) {
  __hip_bfloat16 b = __builtin_bit_cast(__hip_bfloat16, u);
  return __bfloat162float(b);
}

// ---------------- helpers (prep) ----------------

__device__ __forceinline__ float block_sum(float v, float* red) {
  int tid = threadIdx.x;
  red[tid] = v;
  __syncthreads();
  for (int s = 128; s > 0; s >>= 1) {
    if (tid < s) red[tid] += red[tid + s];
    __syncthreads();
  }
  float r = red[0];
  __syncthreads();
  return r;
}

__device__ __forceinline__ float pe_val(float periods, int freqs, int idx, int c) {
  int f = (c < freqs) ? c : (c - freqs);
  float ang = 3.14159265358979323846f / periods * exp2f((float)f) * ((float)idx - 1.0f);
  return (c < freqs) ? sinf(ang) : cosf(ang);
}

__device__ __forceinline__ float pos_feat(int jj, int dy, int mo, int da, int dw) {
  if (jj < 8)  return pe_val(10.f, 4, dy, jj);
  if (jj < 16) return pe_val(12.f, 4, mo, jj - 8);
  if (jj < 28) return pe_val(31.f, 6, da, jj - 16);
  return pe_val(7.f, 4, dw, jj - 28);
}

// ---------------- kernel W: weights -> bf16, transposed [N][Kpad] ----------------
// wqkvT [240][96] (q rows 0-79, k 80-159, v 160-239; each block: 72 real + 8 zero rows)
// woT [80][96], w1T [1152][96], w2T [80][1152]
__global__ __launch_bounds__(256) void wconv_kernel(
    const float* __restrict__ wq, const float* __restrict__ wk,
    const float* __restrict__ wvp, const float* __restrict__ wo,
    const float* __restrict__ w1, const float* __restrict__ w2,
    unsigned short* __restrict__ wqkvT, unsigned short* __restrict__ woT,
    unsigned short* __restrict__ w1T, unsigned short* __restrict__ w2T)
{
  int idx = blockIdx.x * 256 + threadIdx.x;
  if (idx < 23040) {                              // wqkvT
    int n = idx / 96, k = idx % 96;
    int mat = n / 80, nc = n % 80;
    const float* w = (mat == 0) ? wq : (mat == 1) ? wk : wvp;
    wqkvT[idx] = (nc < 72 && k < 72) ? f2b(w[k * 72 + nc]) : (unsigned short)0;
  } else if (idx < 30720) {                       // woT
    int i = idx - 23040;
    int n = i / 96, k = i % 96;
    woT[i] = (n < 72 && k < 72) ? f2b(wo[k * 72 + n]) : (unsigned short)0;
  } else if (idx < 141312) {                      // w1T
    int i = idx - 30720;
    int n = i / 96, k = i % 96;
    w1T[i] = (k < 72) ? f2b(w1[(size_t)k * DFF_ + n]) : (unsigned short)0;
  } else if (idx < 233472) {                      // w2T
    int i = idx - 141312;
    int n = i / DFF_, k = i % DFF_;
    w2T[i] = (n < 72) ? f2b(w2[(size_t)k * 72 + n]) : (unsigned short)0;
  }
}

// ---------------- kernel A: preprocess + patch embed (unchanged from R1) ----------------
__global__ __launch_bounds__(256) void prep_kernel(
    const float* __restrict__ history,
    const float* __restrict__ w_nopos, const float* __restrict__ b_nopos,
    const float* __restrict__ w_wpos, const float* __restrict__ b_wpos,
    const float* __restrict__ task_emb,
    const float* __restrict__ w_inp, const float* __restrict__ b_inp,
    const int* __restrict__ ts, const int* __restrict__ target_ts,
    const int* __restrict__ task,
    float* __restrict__ zbuf, float* __restrict__ sbuf, float* __restrict__ d_out)
{
  const int b = blockIdx.x, tid = threadIdx.x;
  __shared__ float hs[SEQ_][73];
  __shared__ float red[256];
  __shared__ float mu[DM_], rsd[DM_];

  const float* x = history + (size_t)b * T_;

  float xv = (tid < T_) ? x[tid] : 0.0f;
  bool msk1 = (tid < T_) && (xv != 0.0f);
  float sum1 = block_sum(msk1 ? xv : 0.0f, red);
  float cnt1 = block_sum(msk1 ? 1.0f : 0.0f, red);
  float safe1 = fmaxf(cnt1, 1.0f);
  float mean1 = sum1 / safe1;
  float var1 = block_sum(msk1 ? (xv - mean1) * (xv - mean1) : 0.0f, red) / safe1;
  float std1 = (cnt1 > 0.f) ? sqrtf(var1) : 0.0f;
  float mn1  = (cnt1 > 0.f) ? mean1 : 0.0f;
  float hi = mn1 + 2.0f * std1;
  float cl = (tid < T_) ? fminf(fmaxf(xv, 0.0f), hi) : 0.0f;

  bool msk2 = (tid < T_) && (cl != 0.0f);
  float sum2 = block_sum(msk2 ? cl : 0.0f, red);
  float cnt2 = block_sum(msk2 ? 1.0f : 0.0f, red);
  float safe2 = fmaxf(cnt2, 1.0f);
  float mean2 = sum2 / safe2;
  float var2 = block_sum(msk2 ? (cl - mean2) * (cl - mean2) : 0.0f, red) / safe2;
  float std2 = (cnt2 > 0.f) ? sqrtf(var2) : 0.0f;
  float mn2  = (cnt2 > 0.f) ? mean2 : 0.0f;
  const float s = mn2 + std2 + 1e-4f;
  if (tid == 0) { sbuf[b] = s; d_out[B_ + b] = s; }

  const int yr_last = ts[((size_t)b * T_ + (T_ - 1)) * 4 + 0];

  for (int o = tid; o < T_ * DM_; o += 256) {
    int t = o / DM_, j = o % DM_;
    float h = fminf(fmaxf(x[t] / s, 0.0f), 3.0f);
    float val;
    if (j < EMBED_) {
      val = fmaxf(h * w_nopos[j] + b_nopos[j], 0.0f);
    } else {
      int jj = j - EMBED_;
      float e1 = fmaxf(h * w_wpos[jj] + b_wpos[jj], 0.0f);
      const int* tr = ts + ((size_t)b * T_ + t) * 4;
      int dy = min(max(yr_last - tr[0], 0), 10);
      val = e1 + pos_feat(jj, dy, tr[1], tr[2], tr[3]);
    }
    hs[t][j] = val;
  }
  if (tid < DM_) {
    int j = tid;
    float te = task_emb[task[b] * EMBED_ + (j < EMBED_ ? j : j - EMBED_)];
    if (j < EMBED_) {
      hs[T_][j] = te;
    } else {
      int jj = j - EMBED_;
      const int* qr = target_ts + (size_t)b * 5;
      int yq = min(max(yr_last - qr[0], 0), 10);
      hs[T_][j] = te + pos_feat(jj, yq, qr[1], qr[2], qr[3]);
    }
  }
  __syncthreads();

  if (tid < DM_) {
    float acc = 0.f;
    for (int t = 0; t < SEQ_; t++) acc += hs[t][tid];
    float m = acc / (float)SEQ_;
    float v = 0.f;
    for (int t = 0; t < SEQ_; t++) { float d = hs[t][tid] - m; v += d * d; }
    v /= (float)SEQ_;
    mu[tid] = m; rsd[tid] = 1.0f / sqrtf(v + 1e-5f);
  }
  __syncthreads();
  for (int o = tid; o < SEQ_ * DM_; o += 256) {
    int t = o / DM_, d = o % DM_;
    hs[t][d] = (hs[t][d] - mu[d]) * rsd[d];
  }
  __syncthreads();

  for (int o = tid; o < DM_ * PN_ * DM_; o += 256) {
    int j = o % DM_, p = (o / DM_) % PN_, d = o / (DM_ * PN_);
    float acc = b_inp[j];
    #pragma unroll
    for (int i = 0; i < PATCH_; i++) {
      int t = p * STRIDE_ + i;
      if (t > T_) t = T_;
      acc += hs[t][d] * w_inp[i * DM_ + j];
    }
    zbuf[((size_t)(b * DM_ + d) * PN_ + p) * DM_ + j] = acc;
  }
}

// ---------------- kernel B1: QKV + attention + wo + LN1 (MFMA) ----------------
// one block = 16 rows = 192 tokens; 4 waves, each owns 3 M-tiles.
__global__ __launch_bounds__(256) void attn_kernel(
    const unsigned short* __restrict__ wqkvT, const unsigned short* __restrict__ woT,
    const float* __restrict__ bq, const float* __restrict__ bk, const float* __restrict__ bv,
    const float* __restrict__ bo, const float* __restrict__ g1, const float* __restrict__ be1,
    float* __restrict__ zf)
{
  __shared__ __attribute__((aligned(16))) char smem[36864 + 84096];
  unsigned short* zbp  = (unsigned short*)smem;            // [192][96] : z bf16, later o bf16
  unsigned short* qkvp = (unsigned short*)(smem + 36864);  // [3][192][73]
  float* z1f = (float*)(smem + 36864);                     // [192][73] f32 (after attention)

  const int tid = threadIdx.x;
  const int lane = tid & 63, wid = tid >> 6;
  const int m0 = wid * 48;
  const int la = lane & 15, lg = lane >> 4;
  float* zg = zf + (size_t)blockIdx.x * 16 * PN_ * DM_;    // [192][72]

  // 1. z -> zb (bf16, pad cols 72..95 = 0)
  for (int i = tid; i < NTOK * KP; i += 256) {
    int t = i / KP, c = i % KP;
    zbp[i] = (c < 72) ? f2b(zg[t * 72 + c]) : (unsigned short)0;
  }
  __syncthreads();

  // 2. QKV gemm: M=192, N=240 (q|k|v padded to 80 each), K=96
  {
    s8v A[3][3];
    #pragma unroll
    for (int m = 0; m < 3; m++)
      #pragma unroll
      for (int k = 0; k < 3; k++)
        A[m][k] = *(const s8v*)&zbp[(m0 + m * 16 + la) * KP + k * 32 + 8 * lg];

    for (int n0 = 0; n0 < 15; n0++) {
      f32x4 acc[3];
      #pragma unroll
      for (int m = 0; m < 3; m++) { f32x4 z4 = {0.f, 0.f, 0.f, 0.f}; acc[m] = z4; }
      #pragma unroll
      for (int k = 0; k < 3; k++) {
        s8v Bf = *(const s8v*)&wqkvT[(size_t)(n0 * 16 + la) * KP + k * 32 + 8 * lg];
        #pragma unroll
        for (int m = 0; m < 3; m++)
          acc[m] = __builtin_amdgcn_mfma_f32_16x16x32_bf16(A[m][k], Bf, acc[m], 0, 0, 0);
      }
      int ng = n0 * 16 + la;
      int mat = ng / 80, nc = ng % 80;
      if (nc < 72) {
        float bias = (mat == 0 ? bq : mat == 1 ? bk : bv)[nc];
        #pragma unroll
        for (int m = 0; m < 3; m++)
          #pragma unroll
          for (int r = 0; r < 4; r++)
            qkvp[mat * (NTOK * QS) + (m0 + m * 16 + 4 * lg + r) * QS + nc] = f2b(acc[m][r] + bias);
      }
    }
  }
  __syncthreads();

  // 3. attention (scalar). 64 (row,head) pairs, 4 threads each, 3 l per thread.
  //    output o written into zb region (z is dead) with stride 96, pad still 0.
  {
    const int p = tid >> 2, sub = tid & 3;
    const int r = p >> 2, h = p & 3;
    float aw[3][12];
    #pragma unroll
    for (int li = 0; li < 3; li++) {
      const int tq = r * 12 + sub + 4 * li;
      float qv[18];
      #pragma unroll
      for (int e = 0; e < 18; e++) qv[e] = b2f(qkvp[tq * QS + h * 18 + e]);
      float sc[12];
      float mx = -1e30f;
      #pragma unroll
      for (int s2 = 0; s2 < 12; s2++) {
        float acc = 0.f;
        #pragma unroll
        for (int e = 0; e < 18; e++)
          acc += qv[e] * b2f(qkvp[NTOK * QS + (r * 12 + s2) * QS + h * 18 + e]);
        sc[s2] = acc * 0.23570226039551584f;
        mx = fmaxf(mx, sc[s2]);
      }
      float sum = 0.f;
      #pragma unroll
      for (int s2 = 0; s2 < 12; s2++) { sc[s2] = expf(sc[s2] - mx); sum += sc[s2]; }
      float inv = 1.0f / sum;
      #pragma unroll
      for (int s2 = 0; s2 < 12; s2++) aw[li][s2] = sc[s2] * inv;
    }
    #pragma unroll
    for (int li = 0; li < 3; li++) {
      const int tq = r * 12 + sub + 4 * li;
      #pragma unroll
      for (int e = 0; e < 18; e++) {
        float acc = 0.f;
        #pragma unroll
        for (int s2 = 0; s2 < 12; s2++)
          acc += aw[li][s2] * b2f(qkvp[2 * NTOK * QS + (r * 12 + s2) * QS + h * 18 + e]);
        zbp[tq * KP + h * 18 + e] = f2b(acc);
      }
    }
  }
  __syncthreads();

  // 4. wo gemm: A = o (zb region), B = woT; out + bo + z(residual from global) -> z1f
  {
    s8v A[3][3];
    #pragma unroll
    for (int m = 0; m < 3; m++)
      #pragma unroll
      for (int k = 0; k < 3; k++)
        A[m][k] = *(const s8v*)&zbp[(m0 + m * 16 + la) * KP + k * 32 + 8 * lg];

    for (int n0 = 0; n0 < 5; n0++) {
      f32x4 acc[3];
      #pragma unroll
      for (int m = 0; m < 3; m++) { f32x4 z4 = {0.f, 0.f, 0.f, 0.f}; acc[m] = z4; }
      #pragma unroll
      for (int k = 0; k < 3; k++) {
        s8v Bf = *(const s8v*)&woT[(size_t)(n0 * 16 + la) * KP + k * 32 + 8 * lg];
        #pragma unroll
        for (int m = 0; m < 3; m++)
          acc[m] = __builtin_amdgcn_mfma_f32_16x16x32_bf16(A[m][k], Bf, acc[m], 0, 0, 0);
      }
      int j = n0 * 16 + la;
      if (j < 72) {
        float bias = bo[j];
        #pragma unroll
        for (int m = 0; m < 3; m++)
          #pragma unroll
          for (int r = 0; r < 4; r++) {
            int t = m0 + m * 16 + 4 * lg + r;
            z1f[t * 73 + j] = acc[m][r] + bias + zg[t * 72 + j];
          }
      }
    }
  }
  __syncthreads();

  // 5. LN1 -> zf (global, f32)
  if (tid < NTOK) {
    const float* row = z1f + tid * 73;
    float m = 0.f;
    for (int j = 0; j < 72; j++) m += row[j];
    m *= (1.0f / 72.0f);
    float v = 0.f;
    for (int j = 0; j < 72; j++) { float d = row[j] - m; v += d * d; }
    v *= (1.0f / 72.0f);
    float rs = rsqrtf(v + 1e-5f);
    for (int j = 0; j < 72; j++)
      zg[tid * 72 + j] = (row[j] - m) * rs * g1[j] + be1[j];
  }
}

// ---------------- kernel B2: FF + LN2 + LN3 (MFMA) ----------------
__global__ __launch_bounds__(256) void ff_kernel(
    const unsigned short* __restrict__ w1T, const unsigned short* __restrict__ w2T,
    const float* __restrict__ b1, const float* __restrict__ b2,
    const float* __restrict__ g2, const float* __restrict__ be2,
    const float* __restrict__ ge, const float* __restrict__ bee,
    float* __restrict__ zf)
{
  __shared__ __attribute__((aligned(16))) char smem[36864 + 27648];  // zb + a2; z2f overlays
  unsigned short* zbp = (unsigned short*)smem;             // [192][96]
  unsigned short* a2p = (unsigned short*)(smem + 36864);   // [192][72] (64 cols used)
  float* z2f = (float*)smem;                               // [192][73] f32 (after FF)

  const int tid = threadIdx.x;
  const int lane = tid & 63, wid = tid >> 6;
  const int m0 = wid * 48;
  const int la = lane & 15, lg = lane >> 4;
  float* zg = zf + (size_t)blockIdx.x * 16 * PN_ * DM_;

  for (int i = tid; i < NTOK * KP; i += 256) {
    int t = i / KP, c = i % KP;
    zbp[i] = (c < 72) ? f2b(zg[t * 72 + c]) : (unsigned short)0;
  }
  __syncthreads();

  s8v A1[3][3];
  #pragma unroll
  for (int m = 0; m < 3; m++)
    #pragma unroll
    for (int k = 0; k < 3; k++)
      A1[m][k] = *(const s8v*)&zbp[(m0 + m * 16 + la) * KP + k * 32 + 8 * lg];

  f32x4 acc2[3][5];
  #pragma unroll
  for (int m = 0; m < 3; m++)
    #pragma unroll
    for (int n = 0; n < 5; n++) { f32x4 z4 = {0.f, 0.f, 0.f, 0.f}; acc2[m][n] = z4; }

  for (int c = 0; c < 18; c++) {
    // FF1: 4 n-tiles -> gelu -> a2 (bf16)
    #pragma unroll
    for (int nt = 0; nt < 4; nt++) {
      const int ng = (c * 4 + nt) * 16 + la;
      f32x4 acc[3];
      #pragma unroll
      for (int m = 0; m < 3; m++) { f32x4 z4 = {0.f, 0.f, 0.f, 0.f}; acc[m] = z4; }
      #pragma unroll
      for (int k = 0; k < 3; k++) {
        s8v Bf = *(const s8v*)&w1T[(size_t)ng * KP + k * 32 + 8 * lg];
        #pragma unroll
        for (int m = 0; m < 3; m++)
          acc[m] = __builtin_amdgcn_mfma_f32_16x16x32_bf16(A1[m][k], Bf, acc[m], 0, 0, 0);
      }
      const float bias = b1[ng];
      #pragma unroll
      for (int m = 0; m < 3; m++)
        #pragma unroll
        for (int r = 0; r < 4; r++) {
          float x = acc[m][r] + bias;
          float gl = 0.5f * x * (1.0f + erff(x * 0.70710678118654752f));
          a2p[(m0 + m * 16 + 4 * lg + r) * 72 + nt * 16 + la] = f2b(gl);
        }
    }
    __syncthreads();
    // FF2 partial: K-chunk of 64
    s8v A2[3][2];
    #pragma unroll
    for (int m = 0; m < 3; m++)
      #pragma unroll
      for (int k2 = 0; k2 < 2; k2++)
        A2[m][k2] = *(const s8v*)&a2p[(m0 + m * 16 + la) * 72 + k2 * 32 + 8 * lg];
    #pragma unroll
    for (int n0 = 0; n0 < 5; n0++) {
      #pragma unroll
      for (int k2 = 0; k2 < 2; k2++) {
        s8v Bf = *(const s8v*)&w2T[(size_t)(n0 * 16 + la) * DFF_ + c * 64 + k2 * 32 + 8 * lg];
        #pragma unroll
        for (int m = 0; m < 3; m++)
          acc2[m][n0] = __builtin_amdgcn_mfma_f32_16x16x32_bf16(A2[m][k2], Bf, acc2[m][n0], 0, 0, 0);
      }
    }
    __syncthreads();
  }

  // z2 = z1 + ff + b2 -> z2f (overlays zb/a2; all reads done)
  {
    #pragma unroll
    for (int n0 = 0; n0 < 5; n0++) {
      int j = n0 * 16 + la;
      if (j < 72) {
        float bias = b2[j];
        #pragma unroll
        for (int m = 0; m < 3; m++)
          #pragma unroll
          for (int r = 0; r < 4; r++) {
            int t = m0 + m * 16 + 4 * lg + r;
            z2f[t * 73 + j] = acc2[m][n0][r] + bias + zg[t * 72 + j];
          }
      }
    }
  }
  __syncthreads();

  // LN2 then LN3 -> zf global
  if (tid < NTOK) {
    float* row = z2f + tid * 73;
    float m = 0.f;
    for (int j = 0; j < 72; j++) m += row[j];
    m *= (1.0f / 72.0f);
    float v = 0.f;
    for (int j = 0; j < 72; j++) { float d = row[j] - m; v += d * d; }
    v *= (1.0f / 72.0f);
    float rs = rsqrtf(v + 1e-5f);
    for (int j = 0; j < 72; j++) row[j] = (row[j] - m) * rs * g2[j] + be2[j];

    float m2 = 0.f;
    for (int j = 0; j < 72; j++) m2 += row[j];
    m2 *= (1.0f / 72.0f);
    float v2 = 0.f;
    for (int j = 0; j < 72; j++) { float d = row[j] - m2; v2 += d * d; }
    v2 *= (1.0f / 72.0f);
    float rs2 = rsqrtf(v2 + 1e-5f);
    for (int j = 0; j < 72; j++)
      zg[tid * 72 + j] = (row[j] - m2) * rs2 * ge[j] + bee[j];
  }
}

// ---------------- kernel C: output projection + head ----------------
__global__ __launch_bounds__(256) void final_kernel(
    const float* __restrict__ zbuf,
    const float* __restrict__ w_outp, const float* __restrict__ b_outp,
    const float* __restrict__ w_head, const float* __restrict__ b_head,
    const float* __restrict__ sbuf, float* __restrict__ d_out)
{
  const int b = blockIdx.x, tid = threadIdx.x;
  const int wave = tid >> 6, lane = tid & 63;
  __shared__ float out0[DM_];
  const float* zb = zbuf + (size_t)b * DM_ * (PN_ * DM_);

  for (int d = wave; d < DM_; d += 4) {
    float acc = 0.f;
    for (int e = lane; e < PN_ * DM_; e += 64) acc += zb[(size_t)d * PN_ * DM_ + e] * w_outp[e];
    #pragma unroll
    for (int m = 32; m > 0; m >>= 1) acc += __shfl_xor(acc, m, 64);
    if (lane == 0) out0[d] = acc + b_outp[0];
  }
  __syncthreads();
  if (tid == 0) {
    float acc = b_head[0];
    for (int d = 0; d < DM_; d++) acc += out0[d] * w_head[d];
    d_out[b] = fmaxf(acc, 0.0f) * sbuf[b];
  }
}

// ---------------- launcher ----------------
extern "C" void kernel_launch(void* const* d_in, const int* in_sizes, int n_in,
                              void* d_out, int out_size, void* d_ws, size_t ws_size,
                              hipStream_t stream) {
  const float* history  = (const float*)d_in[0];
  const float* w_nopos  = (const float*)d_in[1];
  const float* b_nopos  = (const float*)d_in[2];
  const float* w_wpos   = (const float*)d_in[3];
  const float* b_wpos   = (const float*)d_in[4];
  const float* task_emb = (const float*)d_in[5];
  const float* w_inp    = (const float*)d_in[6];
  const float* b_inp    = (const float*)d_in[7];
  const float* wq = (const float*)d_in[8];
  const float* bq = (const float*)d_in[9];
  const float* wk = (const float*)d_in[10];
  const float* bk = (const float*)d_in[11];
  const float* wv = (const float*)d_in[12];
  const float* bv = (const float*)d_in[13];
  const float* wo = (const float*)d_in[14];
  const float* bo = (const float*)d_in[15];
  const float* w_ff1 = (const float*)d_in[16];
  const float* b_ff1 = (const float*)d_in[17];
  const float* w_ff2 = (const float*)d_in[18];
  const float* b_ff2 = (const float*)d_in[19];
  const float* g1  = (const float*)d_in[20];
  const float* be1 = (const float*)d_in[21];
  const float* g2  = (const float*)d_in[22];
  const float* be2 = (const float*)d_in[23];
  const float* ge  = (const float*)d_in[24];
  const float* bee = (const float*)d_in[25];
  const float* w_outp = (const float*)d_in[26];
  const float* b_outp = (const float*)d_in[27];
  const float* w_head = (const float*)d_in[28];
  const float* b_head = (const float*)d_in[29];
  const int* ts        = (const int*)d_in[30];
  const int* target_ts = (const int*)d_in[31];
  const int* task      = (const int*)d_in[32];

  float* out = (float*)d_out;
  char* ws = (char*)d_ws;
  // ws layout (bytes):
  float* zf   = (float*)ws;                                   // 63,700,992
  float* sbuf = (float*)(ws + 63700992);                      // 1,024
  unsigned short* wqkvT = (unsigned short*)(ws + 63702016);   // 46,080
  unsigned short* woT   = (unsigned short*)(ws + 63748096);   // 15,360
  unsigned short* w1T   = (unsigned short*)(ws + 63763456);   // 221,184
  unsigned short* w2T   = (unsigned short*)(ws + 63984640);   // 184,320  (end 64,168,960)

  wconv_kernel<<<912, 256, 0, stream>>>(wq, wk, wv, wo, w_ff1, w_ff2, wqkvT, woT, w1T, w2T);
  prep_kernel<<<B_, 256, 0, stream>>>(history, w_nopos, b_nopos, w_wpos, b_wpos,
      task_emb, w_inp, b_inp, ts, target_ts, task, zf, sbuf, out);
  attn_kernel<<<1152, 256, 0, stream>>>(wqkvT, woT, bq, bk, bv, bo, g1, be1, zf);
  ff_kernel<<<1152, 256, 0, stream>>>(w1T, w2T, b_ff1, b_ff2, g2, be2, ge, bee, zf);
  final_kernel<<<B_, 256, 0, stream>>>(zf, w_outp, b_outp, w_head, b_head, sbuf, out);
}